// Round 5
// baseline (4363.064 us; speedup 1.0000x reference)
//
#include <hip/hip_runtime.h>

// VectorQuantizer on MI355X — round 5 (= round 4 resubmit, tighter margin).
// x: [32768, 64] f32, codebook: [8192, 64] f32.
// out (f32): [0..2097152) quantized, [2097152] loss, [2097153..) indices as floats.
//
// t_k = x.e_k - ||e_k||^2/2 (per-row argmax == argmin of ref distances) computed
// via mfma_f32_32x32x16_bf16 over K=80 (64 feats + padded [1, -nh, 0...]).
// Pass 1: per-row max of t. Pass 2: gather all candidates with t >= max - 2.5e-4
// (2.3x worst-case bf16 error + ref f32-quantization slop; ~3-4 cands/row).
// Finalize: EXACT rescore of the short list with the round-2-validated
// numpy-replicating numerics + smallest-index tie rule; overflow (> CAP)
// falls back to a full exact scan (statistically never fires).

#define NUM_E   8192
#define DIM     64
#define KPAD    80
#define NROWS   32768
#define NELEM   2097152
#define CAP     48
#define TMARGIN 2.5e-4f
#define NTILES  64          // 2048 cands per wave / 32

using bf16x8 = __attribute__((ext_vector_type(8))) short;
using f32x16 = __attribute__((ext_vector_type(16))) float;

__device__ __forceinline__ unsigned int f2bf(float f) {
    unsigned int u = __float_as_uint(f);
    return (u + 0x7FFFu + ((u >> 16) & 1u)) >> 16;   // RNE to bf16, low 16 bits
}

// numpy pairwise_sum(n=64) of elementwise squares (validated bit-exact r2/r3).
__device__ __forceinline__ float np_sumsq64_f4(const float4 v[16]) {
    float r0 = __fmul_rn(v[0].x, v[0].x), r1 = __fmul_rn(v[0].y, v[0].y);
    float r2 = __fmul_rn(v[0].z, v[0].z), r3 = __fmul_rn(v[0].w, v[0].w);
    float r4 = __fmul_rn(v[1].x, v[1].x), r5 = __fmul_rn(v[1].y, v[1].y);
    float r6 = __fmul_rn(v[1].z, v[1].z), r7 = __fmul_rn(v[1].w, v[1].w);
#pragma unroll
    for (int t = 1; t < 8; ++t) {
        r0 = __fadd_rn(r0, __fmul_rn(v[2 * t].x, v[2 * t].x));
        r1 = __fadd_rn(r1, __fmul_rn(v[2 * t].y, v[2 * t].y));
        r2 = __fadd_rn(r2, __fmul_rn(v[2 * t].z, v[2 * t].z));
        r3 = __fadd_rn(r3, __fmul_rn(v[2 * t].w, v[2 * t].w));
        r4 = __fadd_rn(r4, __fmul_rn(v[2 * t + 1].x, v[2 * t + 1].x));
        r5 = __fadd_rn(r5, __fmul_rn(v[2 * t + 1].y, v[2 * t + 1].y));
        r6 = __fadd_rn(r6, __fmul_rn(v[2 * t + 1].z, v[2 * t + 1].z));
        r7 = __fadd_rn(r7, __fmul_rn(v[2 * t + 1].w, v[2 * t + 1].w));
    }
    return __fadd_rn(__fadd_rn(__fadd_rn(r0, r1), __fadd_rn(r2, r3)),
                     __fadd_rn(__fadd_rn(r4, r5), __fadd_rn(r6, r7)));
}

// cb -> exact norms + padded bf16 rows [e_0..e_63, -norm/2, 0 x15]
__global__ __launch_bounds__(256)
void vq_prep_cb(const float* __restrict__ cb, float* __restrict__ norms,
                unsigned short* __restrict__ ebuf) {
    const int row = blockIdx.x * 256 + threadIdx.x;
    float4 e[16];
    const float4* p = reinterpret_cast<const float4*>(cb + row * DIM);
#pragma unroll
    for (int c = 0; c < 16; ++c) e[c] = p[c];
    const float nrm = np_sumsq64_f4(e);
    norms[row] = nrm;
    uint2* dst = reinterpret_cast<uint2*>(ebuf + (size_t)row * KPAD);
#pragma unroll
    for (int c = 0; c < 16; ++c) {
        uint2 w;
        w.x = f2bf(e[c].x) | (f2bf(e[c].y) << 16);
        w.y = f2bf(e[c].z) | (f2bf(e[c].w) << 16);
        dst[c] = w;
    }
    unsigned int* tail = reinterpret_cast<unsigned int*>(ebuf + (size_t)row * KPAD + DIM);
    tail[0] = f2bf(-0.5f * nrm);
#pragma unroll
    for (int j = 1; j < 8; ++j) tail[j] = 0u;
}

// x -> exact sumsq + padded bf16 rows [x_0..x_63, 1.0, 0 x15]
__global__ __launch_bounds__(256)
void vq_prep_x(const float* __restrict__ x, float* __restrict__ sxa,
               unsigned short* __restrict__ xbuf) {
    const int row = blockIdx.x * 256 + threadIdx.x;
    float4 v[16];
    const float4* p = reinterpret_cast<const float4*>(x + row * DIM);
#pragma unroll
    for (int c = 0; c < 16; ++c) v[c] = p[c];
    sxa[row] = np_sumsq64_f4(v);
    uint2* dst = reinterpret_cast<uint2*>(xbuf + (size_t)row * KPAD);
#pragma unroll
    for (int c = 0; c < 16; ++c) {
        uint2 w;
        w.x = f2bf(v[c].x) | (f2bf(v[c].y) << 16);
        w.y = f2bf(v[c].z) | (f2bf(v[c].w) << 16);
        dst[c] = w;
    }
    unsigned int* tail = reinterpret_cast<unsigned int*>(xbuf + (size_t)row * KPAD + DIM);
    tail[0] = 0x3F80u;   // bf16(1.0)
#pragma unroll
    for (int j = 1; j < 8; ++j) tail[j] = 0u;
}

// MFMA filter: block = 4 waves; wave = 64 x-rows x 2048-cand split.
// A = cb tile (M=cands), B = x rows (N=xrows). C[cand][xrow]:
// col=lane&31, row=(reg&3)+8*(reg>>2)+4*(lane>>5).
__global__ __launch_bounds__(256)
void vq_mfma_kernel(const unsigned short* __restrict__ ebuf,
                    const unsigned short* __restrict__ xbuf,
                    int* __restrict__ cnt, int* __restrict__ slots) {
    const int tid  = threadIdx.x;
    const int lane = tid & 63;
    const int wid  = tid >> 6;         // candidate split 0..3
    const int half = lane >> 5;        // k-half of the fragment
    const int l31  = lane & 31;
    const int rowbase  = blockIdx.x * 64;
    const int candbase = wid * 2048;

    // B fragments (x rows), persistent across all tiles
    bf16x8 bfrag[2][5];
#pragma unroll
    for (int rt = 0; rt < 2; ++rt)
#pragma unroll
        for (int ks = 0; ks < 5; ++ks)
            bfrag[rt][ks] = *reinterpret_cast<const bf16x8*>(
                xbuf + (size_t)(rowbase + rt * 32 + l31) * KPAD + ks * 16 + half * 8);

    const unsigned short* abase = ebuf + (size_t)(candbase + l31) * KPAD + half * 8;

    float vmax0 = -3.402823466e+38f, vmax1 = -3.402823466e+38f;

    for (int tile = 0; tile < NTILES; ++tile) {
        const unsigned short* ap = abase + (size_t)tile * 32 * KPAD;
        bf16x8 af[5];
#pragma unroll
        for (int ks = 0; ks < 5; ++ks)
            af[ks] = *reinterpret_cast<const bf16x8*>(ap + ks * 16);
        f32x16 acc;
#pragma unroll
        for (int i = 0; i < 16; ++i) acc[i] = 0.f;
#pragma unroll
        for (int ks = 0; ks < 5; ++ks)
            acc = __builtin_amdgcn_mfma_f32_32x32x16_bf16(af[ks], bfrag[0][ks], acc, 0, 0, 0);
#pragma unroll
        for (int i = 0; i < 16; ++i) vmax0 = fmaxf(vmax0, acc[i]);
#pragma unroll
        for (int i = 0; i < 16; ++i) acc[i] = 0.f;
#pragma unroll
        for (int ks = 0; ks < 5; ++ks)
            acc = __builtin_amdgcn_mfma_f32_32x32x16_bf16(af[ks], bfrag[1][ks], acc, 0, 0, 0);
#pragma unroll
        for (int i = 0; i < 16; ++i) vmax1 = fmaxf(vmax1, acc[i]);
    }

    // fold lane halves, merge the 4 splits in LDS
    vmax0 = fmaxf(vmax0, __shfl_xor(vmax0, 32));
    vmax1 = fmaxf(vmax1, __shfl_xor(vmax1, 32));
    __shared__ float sm[4][2][32];
    __shared__ float sm2[2][32];
    if (half == 0) { sm[wid][0][l31] = vmax0; sm[wid][1][l31] = vmax1; }
    __syncthreads();
    if (tid < 64) {
        const int rt = tid >> 5, xr = tid & 31;
        sm2[rt][xr] = fmaxf(fmaxf(sm[0][rt][xr], sm[1][rt][xr]),
                            fmaxf(sm[2][rt][xr], sm[3][rt][xr]));
    }
    __syncthreads();
    const float thr0 = sm2[0][l31] - TMARGIN;
    const float thr1 = sm2[1][l31] - TMARGIN;

    // pass 2: recompute (bit-identical) and gather candidates above threshold
    for (int tile = 0; tile < NTILES; ++tile) {
        const unsigned short* ap = abase + (size_t)tile * 32 * KPAD;
        bf16x8 af[5];
#pragma unroll
        for (int ks = 0; ks < 5; ++ks)
            af[ks] = *reinterpret_cast<const bf16x8*>(ap + ks * 16);
#pragma unroll
        for (int rt = 0; rt < 2; ++rt) {
            const float thr = rt ? thr1 : thr0;
            f32x16 acc;
#pragma unroll
            for (int i = 0; i < 16; ++i) acc[i] = 0.f;
#pragma unroll
            for (int ks = 0; ks < 5; ++ks)
                acc = __builtin_amdgcn_mfma_f32_32x32x16_bf16(af[ks], bfrag[rt][ks], acc, 0, 0, 0);
            float tm = acc[0];
#pragma unroll
            for (int i = 1; i < 16; ++i) tm = fmaxf(tm, acc[i]);
            if (__any(tm >= thr)) {
                const int grow = rowbase + rt * 32 + l31;
#pragma unroll
                for (int r = 0; r < 16; ++r) {
                    if (acc[r] >= thr) {
                        const int crow = (r & 3) + 8 * (r >> 2) + 4 * half;
                        const int cand = candbase + tile * 32 + crow;
                        const int pos = atomicAdd(&cnt[grow], 1);
                        if (pos < CAP) slots[grow * CAP + pos] = cand;
                    }
                }
            }
        }
    }
}

// Exact rescore of the short list (validated numerics), gather + loss.
__global__ __launch_bounds__(256)
void vq_finalize_kernel(const float* __restrict__ x, const float* __restrict__ cb,
                        const float* __restrict__ norms, const float* __restrict__ sxa,
                        const int* __restrict__ cnt, const int* __restrict__ slots,
                        float* __restrict__ out_q, float* __restrict__ out_idx,
                        float* __restrict__ loss_acc) {
    const int r = blockIdx.x * 256 + threadIdx.x;
    float4 xr[16];
    const float4* xp = reinterpret_cast<const float4*>(x + r * DIM);
#pragma unroll
    for (int c = 0; c < 16; ++c) xr[c] = xp[c];
    const float sx = sxa[r];

    float best = 3.402823466e+38f;
    int bi = 0x7FFFFFFF;
    const int c0 = cnt[r];
    const int nlist = (c0 <= CAP) ? c0 : NUM_E;   // overflow -> full exact scan
    for (int i = 0; i < nlist; ++i) {
        const int k = (c0 <= CAP) ? slots[r * CAP + i] : i;
        const float* ep = cb + (size_t)k * DIM;
        float dot = 0.f;
#pragma unroll
        for (int c = 0; c < 16; ++c) {
            dot = fmaf(xr[c].x, ep[4 * c + 0], dot);
            dot = fmaf(xr[c].y, ep[4 * c + 1], dot);
            dot = fmaf(xr[c].z, ep[4 * c + 2], dot);
            dot = fmaf(xr[c].w, ep[4 * c + 3], dot);
        }
        const float t1 = __fadd_rn(sx, norms[k]);
        const float d2 = __fadd_rn(dot, dot);
        const float sc = __fsub_rn(t1, d2);
        if (sc < best || (sc == best && k < bi)) { best = sc; bi = k; }  // first-min
    }
    out_idx[r] = (float)bi;

    const float4* ep = reinterpret_cast<const float4*>(cb + (size_t)bi * DIM);
    float4* qp = reinterpret_cast<float4*>(out_q + r * DIM);
    float s2 = 0.f;
#pragma unroll
    for (int c = 0; c < 16; ++c) {
        float4 e4 = ep[c];
        float4 x4 = xr[c];
        qp[c] = e4;
        float dx = e4.x - x4.x; s2 = fmaf(dx, dx, s2);
        dx = e4.y - x4.y; s2 = fmaf(dx, dx, s2);
        dx = e4.z - x4.z; s2 = fmaf(dx, dx, s2);
        dx = e4.w - x4.w; s2 = fmaf(dx, dx, s2);
    }
#pragma unroll
    for (int off = 32; off >= 1; off >>= 1) s2 += __shfl_xor(s2, off);
    __shared__ float wsum[4];
    const int lane = threadIdx.x & 63, wv = threadIdx.x >> 6;
    if (lane == 0) wsum[wv] = s2;
    __syncthreads();
    if (threadIdx.x == 0)
        atomicAdd(loss_acc, (wsum[0] + wsum[1]) + (wsum[2] + wsum[3]));
}

__global__ void vq_loss_kernel(const float* __restrict__ loss_acc,
                               float* __restrict__ out_loss) {
    if (threadIdx.x == 0 && blockIdx.x == 0)
        *out_loss = *loss_acc * (1.25f / (float)NELEM);
}

extern "C" void kernel_launch(void* const* d_in, const int* in_sizes, int n_in,
                              void* d_out, int out_size, void* d_ws, size_t ws_size,
                              hipStream_t stream) {
    const float* x  = (const float*)d_in[0];
    const float* cb = (const float*)d_in[1];

    float* out_q    = (float*)d_out;
    float* out_loss = (float*)d_out + NELEM;
    float* out_idx  = (float*)d_out + NELEM + 1;

    // ws layout (16B-aligned sections)
    float* wsf      = (float*)d_ws;
    float* loss_acc = wsf;                               // 64 floats
    float* norms    = wsf + 64;                          // 8192
    float* sxa      = norms + NUM_E;                     // 32768
    int*   cnt      = (int*)(sxa + NROWS);               // 32768
    int*   slots    = cnt + NROWS;                       // 32768*CAP
    unsigned short* ebuf = (unsigned short*)(slots + (size_t)NROWS * CAP); // 8192*80
    unsigned short* xbuf = ebuf + (size_t)NUM_E * KPAD;  // 32768*80

    hipMemsetAsync(loss_acc, 0, 64 * sizeof(float), stream);
    hipMemsetAsync(cnt, 0, NROWS * sizeof(int), stream);
    vq_prep_cb<<<NUM_E / 256, 256, 0, stream>>>(cb, norms, ebuf);
    vq_prep_x<<<NROWS / 256, 256, 0, stream>>>(x, sxa, xbuf);
    vq_mfma_kernel<<<NROWS / 64, 256, 0, stream>>>(ebuf, xbuf, cnt, slots);
    vq_finalize_kernel<<<NROWS / 256, 256, 0, stream>>>(x, cb, norms, sxa, cnt, slots,
                                                        out_q, out_idx, loss_acc);
    vq_loss_kernel<<<1, 64, 0, stream>>>(loss_acc, out_loss);
}

// Round 6
// 288.466 us; speedup vs baseline: 15.1250x; 15.1250x over previous
//
#include <hip/hip_runtime.h>

// VectorQuantizer on MI355X — round 6: wave-cooperative finalize.
// x: [32768, 64] f32, codebook: [8192, 64] f32.
// out (f32): [0..2097152) quantized, [2097152] loss, [2097153..) indices as floats.
//
// bf16-MFMA filter (t_k = x.e_k - ||e_k||^2/2, margin 2.5e-4) + exact rescore.
// Finalize is ONE WAVE PER ROW: lanes split the candidate list, so the
// CAP-overflow full-scan fallback costs 128 wave-parallel iterations (~16us)
// instead of 8192 serial ones (~4ms in round 5). Per-candidate numerics are
// the round-2-validated numpy replication; first-index tie rule via
// lexicographic (score, idx) wave reduction.

#define NUM_E   8192
#define DIM     64
#define KPAD    80
#define NROWS   32768
#define NELEM   2097152
#define CAP     64
#define TMARGIN 2.5e-4f
#define NTILES  64          // 2048 cands per wave / 32

using bf16x8 = __attribute__((ext_vector_type(8))) short;
using f32x16 = __attribute__((ext_vector_type(16))) float;

__device__ __forceinline__ unsigned int f2bf(float f) {
    unsigned int u = __float_as_uint(f);
    return (u + 0x7FFFu + ((u >> 16) & 1u)) >> 16;   // RNE to bf16, low 16 bits
}

// numpy pairwise_sum(n=64) of elementwise squares (validated bit-exact r2/r3).
__device__ __forceinline__ float np_sumsq64_f4(const float4 v[16]) {
    float r0 = __fmul_rn(v[0].x, v[0].x), r1 = __fmul_rn(v[0].y, v[0].y);
    float r2 = __fmul_rn(v[0].z, v[0].z), r3 = __fmul_rn(v[0].w, v[0].w);
    float r4 = __fmul_rn(v[1].x, v[1].x), r5 = __fmul_rn(v[1].y, v[1].y);
    float r6 = __fmul_rn(v[1].z, v[1].z), r7 = __fmul_rn(v[1].w, v[1].w);
#pragma unroll
    for (int t = 1; t < 8; ++t) {
        r0 = __fadd_rn(r0, __fmul_rn(v[2 * t].x, v[2 * t].x));
        r1 = __fadd_rn(r1, __fmul_rn(v[2 * t].y, v[2 * t].y));
        r2 = __fadd_rn(r2, __fmul_rn(v[2 * t].z, v[2 * t].z));
        r3 = __fadd_rn(r3, __fmul_rn(v[2 * t].w, v[2 * t].w));
        r4 = __fadd_rn(r4, __fmul_rn(v[2 * t + 1].x, v[2 * t + 1].x));
        r5 = __fadd_rn(r5, __fmul_rn(v[2 * t + 1].y, v[2 * t + 1].y));
        r6 = __fadd_rn(r6, __fmul_rn(v[2 * t + 1].z, v[2 * t + 1].z));
        r7 = __fadd_rn(r7, __fmul_rn(v[2 * t + 1].w, v[2 * t + 1].w));
    }
    return __fadd_rn(__fadd_rn(__fadd_rn(r0, r1), __fadd_rn(r2, r3)),
                     __fadd_rn(__fadd_rn(r4, r5), __fadd_rn(r6, r7)));
}

// cb -> exact norms + padded bf16 rows [e_0..e_63, -norm/2, 0 x15]
__global__ __launch_bounds__(256)
void vq_prep_cb(const float* __restrict__ cb, float* __restrict__ norms,
                unsigned short* __restrict__ ebuf) {
    const int row = blockIdx.x * 256 + threadIdx.x;
    float4 e[16];
    const float4* p = reinterpret_cast<const float4*>(cb + row * DIM);
#pragma unroll
    for (int c = 0; c < 16; ++c) e[c] = p[c];
    const float nrm = np_sumsq64_f4(e);
    norms[row] = nrm;
    uint2* dst = reinterpret_cast<uint2*>(ebuf + (size_t)row * KPAD);
#pragma unroll
    for (int c = 0; c < 16; ++c) {
        uint2 w;
        w.x = f2bf(e[c].x) | (f2bf(e[c].y) << 16);
        w.y = f2bf(e[c].z) | (f2bf(e[c].w) << 16);
        dst[c] = w;
    }
    unsigned int* tail = reinterpret_cast<unsigned int*>(ebuf + (size_t)row * KPAD + DIM);
    tail[0] = f2bf(-0.5f * nrm);
#pragma unroll
    for (int j = 1; j < 8; ++j) tail[j] = 0u;
}

// x -> exact sumsq + padded bf16 rows [x_0..x_63, 1.0, 0 x15]
__global__ __launch_bounds__(256)
void vq_prep_x(const float* __restrict__ x, float* __restrict__ sxa,
               unsigned short* __restrict__ xbuf) {
    const int row = blockIdx.x * 256 + threadIdx.x;
    float4 v[16];
    const float4* p = reinterpret_cast<const float4*>(x + row * DIM);
#pragma unroll
    for (int c = 0; c < 16; ++c) v[c] = p[c];
    sxa[row] = np_sumsq64_f4(v);
    uint2* dst = reinterpret_cast<uint2*>(xbuf + (size_t)row * KPAD);
#pragma unroll
    for (int c = 0; c < 16; ++c) {
        uint2 w;
        w.x = f2bf(v[c].x) | (f2bf(v[c].y) << 16);
        w.y = f2bf(v[c].z) | (f2bf(v[c].w) << 16);
        dst[c] = w;
    }
    unsigned int* tail = reinterpret_cast<unsigned int*>(xbuf + (size_t)row * KPAD + DIM);
    tail[0] = 0x3F80u;   // bf16(1.0)
#pragma unroll
    for (int j = 1; j < 8; ++j) tail[j] = 0u;
}

// MFMA filter: block = 4 waves; wave = 64 x-rows x 2048-cand split.
// A = cb tile (M=cands), B = x rows (N=xrows). C[cand][xrow]:
// col=lane&31, row=(reg&3)+8*(reg>>2)+4*(lane>>5).
__global__ __launch_bounds__(256)
void vq_mfma_kernel(const unsigned short* __restrict__ ebuf,
                    const unsigned short* __restrict__ xbuf,
                    int* __restrict__ cnt, int* __restrict__ slots) {
    const int tid  = threadIdx.x;
    const int lane = tid & 63;
    const int wid  = tid >> 6;         // candidate split 0..3
    const int half = lane >> 5;        // k-half of the fragment
    const int l31  = lane & 31;
    const int rowbase  = blockIdx.x * 64;
    const int candbase = wid * 2048;

    // B fragments (x rows), persistent across all tiles
    bf16x8 bfrag[2][5];
#pragma unroll
    for (int rt = 0; rt < 2; ++rt)
#pragma unroll
        for (int ks = 0; ks < 5; ++ks)
            bfrag[rt][ks] = *reinterpret_cast<const bf16x8*>(
                xbuf + (size_t)(rowbase + rt * 32 + l31) * KPAD + ks * 16 + half * 8);

    const unsigned short* abase = ebuf + (size_t)(candbase + l31) * KPAD + half * 8;

    float vmax0 = -3.402823466e+38f, vmax1 = -3.402823466e+38f;

    for (int tile = 0; tile < NTILES; ++tile) {
        const unsigned short* ap = abase + (size_t)tile * 32 * KPAD;
        bf16x8 af[5];
#pragma unroll
        for (int ks = 0; ks < 5; ++ks)
            af[ks] = *reinterpret_cast<const bf16x8*>(ap + ks * 16);
        f32x16 acc;
#pragma unroll
        for (int i = 0; i < 16; ++i) acc[i] = 0.f;
#pragma unroll
        for (int ks = 0; ks < 5; ++ks)
            acc = __builtin_amdgcn_mfma_f32_32x32x16_bf16(af[ks], bfrag[0][ks], acc, 0, 0, 0);
#pragma unroll
        for (int i = 0; i < 16; ++i) vmax0 = fmaxf(vmax0, acc[i]);
#pragma unroll
        for (int i = 0; i < 16; ++i) acc[i] = 0.f;
#pragma unroll
        for (int ks = 0; ks < 5; ++ks)
            acc = __builtin_amdgcn_mfma_f32_32x32x16_bf16(af[ks], bfrag[1][ks], acc, 0, 0, 0);
#pragma unroll
        for (int i = 0; i < 16; ++i) vmax1 = fmaxf(vmax1, acc[i]);
    }

    // fold lane halves, merge the 4 splits in LDS
    vmax0 = fmaxf(vmax0, __shfl_xor(vmax0, 32));
    vmax1 = fmaxf(vmax1, __shfl_xor(vmax1, 32));
    __shared__ float sm[4][2][32];
    __shared__ float sm2[2][32];
    if (half == 0) { sm[wid][0][l31] = vmax0; sm[wid][1][l31] = vmax1; }
    __syncthreads();
    if (tid < 64) {
        const int rt = tid >> 5, xr = tid & 31;
        sm2[rt][xr] = fmaxf(fmaxf(sm[0][rt][xr], sm[1][rt][xr]),
                            fmaxf(sm[2][rt][xr], sm[3][rt][xr]));
    }
    __syncthreads();
    const float thr0 = sm2[0][l31] - TMARGIN;
    const float thr1 = sm2[1][l31] - TMARGIN;

    // pass 2: recompute (bit-identical) and gather candidates above threshold
    for (int tile = 0; tile < NTILES; ++tile) {
        const unsigned short* ap = abase + (size_t)tile * 32 * KPAD;
        bf16x8 af[5];
#pragma unroll
        for (int ks = 0; ks < 5; ++ks)
            af[ks] = *reinterpret_cast<const bf16x8*>(ap + ks * 16);
#pragma unroll
        for (int rt = 0; rt < 2; ++rt) {
            const float thr = rt ? thr1 : thr0;
            f32x16 acc;
#pragma unroll
            for (int i = 0; i < 16; ++i) acc[i] = 0.f;
#pragma unroll
            for (int ks = 0; ks < 5; ++ks)
                acc = __builtin_amdgcn_mfma_f32_32x32x16_bf16(af[ks], bfrag[rt][ks], acc, 0, 0, 0);
            float tm = acc[0];
#pragma unroll
            for (int i = 1; i < 16; ++i) tm = fmaxf(tm, acc[i]);
            if (__any(tm >= thr)) {
                const int grow = rowbase + rt * 32 + l31;
#pragma unroll
                for (int r = 0; r < 16; ++r) {
                    if (acc[r] >= thr) {
                        const int crow = (r & 3) + 8 * (r >> 2) + 4 * half;
                        const int cand = candbase + tile * 32 + crow;
                        const int pos = atomicAdd(&cnt[grow], 1);
                        if (pos < CAP) slots[grow * CAP + pos] = cand;
                    }
                }
            }
        }
    }
}

// Wave-per-row exact rescore (validated numerics), gather + loss partials.
__global__ __launch_bounds__(256)
void vq_finalize_kernel(const float* __restrict__ x, const float* __restrict__ cb,
                        const float* __restrict__ norms, const float* __restrict__ sxa,
                        const int* __restrict__ cnt, const int* __restrict__ slots,
                        float* __restrict__ out_q, float* __restrict__ out_idx,
                        float* __restrict__ block_loss) {
    const int lane = threadIdx.x & 63;
    const int wv   = threadIdx.x >> 6;
    const int r    = blockIdx.x * 4 + wv;

    // full x row per lane (wave-uniform address)
    float4 xr[16];
    const float4* xp = reinterpret_cast<const float4*>(x + (size_t)r * DIM);
#pragma unroll
    for (int c = 0; c < 16; ++c) xr[c] = xp[c];
    const float sx = sxa[r];

    const int c0 = cnt[r];
    const bool ok = (c0 <= CAP);
    const int nlist = ok ? c0 : NUM_E;   // overflow -> wave-parallel full scan

    float best = 3.402823466e+38f;
    int bi = 0x7FFFFFFF;
    for (int i = lane; i < nlist; i += 64) {
        const int k = ok ? slots[r * CAP + i] : i;
        const float* ep = cb + (size_t)k * DIM;
        float dot = 0.f;   // sequential fmaf chain d=0..63 (exact replication)
#pragma unroll
        for (int c = 0; c < 16; ++c) {
            dot = fmaf(xr[c].x, ep[4 * c + 0], dot);
            dot = fmaf(xr[c].y, ep[4 * c + 1], dot);
            dot = fmaf(xr[c].z, ep[4 * c + 2], dot);
            dot = fmaf(xr[c].w, ep[4 * c + 3], dot);
        }
        const float t1 = __fadd_rn(sx, norms[k]);
        const float d2 = __fadd_rn(dot, dot);
        const float sc = __fsub_rn(t1, d2);
        if (sc < best || (sc == best && k < bi)) { best = sc; bi = k; }
    }
    // wave-reduce lexicographic min (score, index) — exact first-min rule
#pragma unroll
    for (int off = 1; off < 64; off <<= 1) {
        const float s2 = __shfl_xor(best, off);
        const int   i2 = __shfl_xor(bi, off);
        if (s2 < best || (s2 == best && i2 < bi)) { best = s2; bi = i2; }
    }

    // lane d handles element d: coalesced gather/store + loss partial
    const float ed = cb[(size_t)bi * DIM + lane];
    const float xd = x[(size_t)r * DIM + lane];
    out_q[(size_t)r * DIM + lane] = ed;
    if (lane == 0) out_idx[r] = (float)bi;
    float dd = ed - xd;
    dd = dd * dd;
#pragma unroll
    for (int off = 1; off < 64; off <<= 1) dd += __shfl_xor(dd, off);

    __shared__ float wsum[4];
    if (lane == 0) wsum[wv] = dd;
    __syncthreads();
    if (threadIdx.x == 0)
        block_loss[blockIdx.x] = (wsum[0] + wsum[1]) + (wsum[2] + wsum[3]);
}

// Sum 8192 per-block loss partials (single block, contention-free).
__global__ __launch_bounds__(256)
void vq_loss_kernel(const float* __restrict__ block_loss,
                    float* __restrict__ out_loss) {
    float s = 0.f;
    for (int i = threadIdx.x; i < NROWS / 4; i += 256) s += block_loss[i];
#pragma unroll
    for (int off = 1; off < 64; off <<= 1) s += __shfl_xor(s, off);
    __shared__ float wsum[4];
    const int lane = threadIdx.x & 63, wv = threadIdx.x >> 6;
    if (lane == 0) wsum[wv] = s;
    __syncthreads();
    if (threadIdx.x == 0)
        *out_loss = ((wsum[0] + wsum[1]) + (wsum[2] + wsum[3])) * (1.25f / (float)NELEM);
}

extern "C" void kernel_launch(void* const* d_in, const int* in_sizes, int n_in,
                              void* d_out, int out_size, void* d_ws, size_t ws_size,
                              hipStream_t stream) {
    const float* x  = (const float*)d_in[0];
    const float* cb = (const float*)d_in[1];

    float* out_q    = (float*)d_out;
    float* out_loss = (float*)d_out + NELEM;
    float* out_idx  = (float*)d_out + NELEM + 1;

    // ws layout (16B-aligned sections)
    float* wsf        = (float*)d_ws;
    float* block_loss = wsf;                               // 8192 floats
    float* norms      = wsf + NROWS / 4;                   // 8192
    float* sxa        = norms + NUM_E;                     // 32768
    int*   cnt        = (int*)(sxa + NROWS);               // 32768
    int*   slots      = cnt + NROWS;                       // 32768*CAP
    unsigned short* ebuf = (unsigned short*)(slots + (size_t)NROWS * CAP); // 8192*80
    unsigned short* xbuf = ebuf + (size_t)NUM_E * KPAD;    // 32768*80

    hipMemsetAsync(cnt, 0, NROWS * sizeof(int), stream);
    vq_prep_cb<<<NUM_E / 256, 256, 0, stream>>>(cb, norms, ebuf);
    vq_prep_x<<<NROWS / 256, 256, 0, stream>>>(x, sxa, xbuf);
    vq_mfma_kernel<<<NROWS / 64, 256, 0, stream>>>(ebuf, xbuf, cnt, slots);
    vq_finalize_kernel<<<NROWS / 4, 256, 0, stream>>>(x, cb, norms, sxa, cnt, slots,
                                                      out_q, out_idx, block_loss);
    vq_loss_kernel<<<1, 256, 0, stream>>>(block_loss, out_loss);
}

// Round 7
// 198.099 us; speedup vs baseline: 22.0246x; 1.4562x over previous
//
#include <hip/hip_runtime.h>

// VectorQuantizer on MI355X — round 7: fused high-occupancy MFMA filter.
// x: [32768, 64] f32, codebook: [8192, 64] f32.
// out (f32): [0..2097152) quantized, [2097152] loss, [2097153..) indices as floats.
//
// Block = 512 thr (8 waves) x 64 rows; wave w covers cands [w*1024, w*1024+1024)
// (32 tiles of 32). Grid = 512 blocks -> 16 waves/CU (2x round 6).
// Pass 1: per-row max of t_k = x.e_k - ||e_k||^2/2 (bf16 MFMA, K=80), with
//   reg-double-buffered A loads and depth-4 fmax trees (no long chains).
// Pass 2: recompute (bit-identical) + gather cands >= rowmax - 2.5e-4 into LDS.
// Fused finalize: wave-parallel EXACT rescore (validated numpy-replicating
//   numerics, first-min tie rule) + gather + loss partials. Overflow (>CAP)
//   falls back to wave-parallel full scan (~14us, not 4ms).

#define NUM_E   8192
#define DIM     64
#define KPAD    80
#define NROWS   32768
#define NELEM   2097152
#define CAP     64
#define TMARGIN 2.5e-4f
#define ROWS_PB 64
#define WAVES   8
#define NT      32          // tiles of 32 cands per wave
#define FLTMAX  3.402823466e+38f

using bf16x8 = __attribute__((ext_vector_type(8))) short;
using f32x16 = __attribute__((ext_vector_type(16))) float;

__device__ __forceinline__ unsigned int f2bf(float f) {
    unsigned int u = __float_as_uint(f);
    return (u + 0x7FFFu + ((u >> 16) & 1u)) >> 16;   // RNE to bf16
}

// numpy pairwise_sum(n=64) of elementwise squares (validated bit-exact r2+).
__device__ __forceinline__ float np_sumsq64_f4(const float4 v[16]) {
    float r0 = __fmul_rn(v[0].x, v[0].x), r1 = __fmul_rn(v[0].y, v[0].y);
    float r2 = __fmul_rn(v[0].z, v[0].z), r3 = __fmul_rn(v[0].w, v[0].w);
    float r4 = __fmul_rn(v[1].x, v[1].x), r5 = __fmul_rn(v[1].y, v[1].y);
    float r6 = __fmul_rn(v[1].z, v[1].z), r7 = __fmul_rn(v[1].w, v[1].w);
#pragma unroll
    for (int t = 1; t < 8; ++t) {
        r0 = __fadd_rn(r0, __fmul_rn(v[2 * t].x, v[2 * t].x));
        r1 = __fadd_rn(r1, __fmul_rn(v[2 * t].y, v[2 * t].y));
        r2 = __fadd_rn(r2, __fmul_rn(v[2 * t].z, v[2 * t].z));
        r3 = __fadd_rn(r3, __fmul_rn(v[2 * t].w, v[2 * t].w));
        r4 = __fadd_rn(r4, __fmul_rn(v[2 * t + 1].x, v[2 * t + 1].x));
        r5 = __fadd_rn(r5, __fmul_rn(v[2 * t + 1].y, v[2 * t + 1].y));
        r6 = __fadd_rn(r6, __fmul_rn(v[2 * t + 1].z, v[2 * t + 1].z));
        r7 = __fadd_rn(r7, __fmul_rn(v[2 * t + 1].w, v[2 * t + 1].w));
    }
    return __fadd_rn(__fadd_rn(__fadd_rn(r0, r1), __fadd_rn(r2, r3)),
                     __fadd_rn(__fadd_rn(r4, r5), __fadd_rn(r6, r7)));
}

__global__ __launch_bounds__(256)
void vq_prep_cb(const float* __restrict__ cb, float* __restrict__ norms,
                unsigned short* __restrict__ ebuf) {
    const int row = blockIdx.x * 256 + threadIdx.x;
    float4 e[16];
    const float4* p = reinterpret_cast<const float4*>(cb + row * DIM);
#pragma unroll
    for (int c = 0; c < 16; ++c) e[c] = p[c];
    const float nrm = np_sumsq64_f4(e);
    norms[row] = nrm;
    uint2* dst = reinterpret_cast<uint2*>(ebuf + (size_t)row * KPAD);
#pragma unroll
    for (int c = 0; c < 16; ++c) {
        uint2 w;
        w.x = f2bf(e[c].x) | (f2bf(e[c].y) << 16);
        w.y = f2bf(e[c].z) | (f2bf(e[c].w) << 16);
        dst[c] = w;
    }
    unsigned int* tail = reinterpret_cast<unsigned int*>(ebuf + (size_t)row * KPAD + DIM);
    tail[0] = f2bf(-0.5f * nrm);
#pragma unroll
    for (int j = 1; j < 8; ++j) tail[j] = 0u;
}

__global__ __launch_bounds__(256)
void vq_prep_x(const float* __restrict__ x, float* __restrict__ sxa,
               unsigned short* __restrict__ xbuf) {
    const int row = blockIdx.x * 256 + threadIdx.x;
    float4 v[16];
    const float4* p = reinterpret_cast<const float4*>(x + row * DIM);
#pragma unroll
    for (int c = 0; c < 16; ++c) v[c] = p[c];
    sxa[row] = np_sumsq64_f4(v);
    uint2* dst = reinterpret_cast<uint2*>(xbuf + (size_t)row * KPAD);
#pragma unroll
    for (int c = 0; c < 16; ++c) {
        uint2 w;
        w.x = f2bf(v[c].x) | (f2bf(v[c].y) << 16);
        w.y = f2bf(v[c].z) | (f2bf(v[c].w) << 16);
        dst[c] = w;
    }
    unsigned int* tail = reinterpret_cast<unsigned int*>(xbuf + (size_t)row * KPAD + DIM);
    tail[0] = 0x3F80u;   // bf16(1.0)
#pragma unroll
    for (int j = 1; j < 8; ++j) tail[j] = 0u;
}

// 5 dependent MFMAs + depth-4 max tree folded into running max DST.
#define TILE_MAX(AF, RT, DST) do {                                              \
    f32x16 acc_;                                                                \
    _Pragma("unroll") for (int i_ = 0; i_ < 16; ++i_) acc_[i_] = 0.f;           \
    _Pragma("unroll") for (int k_ = 0; k_ < 5; ++k_)                            \
        acc_ = __builtin_amdgcn_mfma_f32_32x32x16_bf16(AF[k_], bfrag[RT][k_],   \
                                                       acc_, 0, 0, 0);          \
    float m0_ = fmaxf(fmaxf(acc_[0], acc_[1]),  fmaxf(acc_[2], acc_[3]));       \
    float m1_ = fmaxf(fmaxf(acc_[4], acc_[5]),  fmaxf(acc_[6], acc_[7]));       \
    float m2_ = fmaxf(fmaxf(acc_[8], acc_[9]),  fmaxf(acc_[10], acc_[11]));     \
    float m3_ = fmaxf(fmaxf(acc_[12], acc_[13]), fmaxf(acc_[14], acc_[15]));    \
    DST = fmaxf(DST, fmaxf(fmaxf(m0_, m1_), fmaxf(m2_, m3_)));                  \
} while (0)

// Recompute (bit-identical) + gather cands above per-row threshold into LDS.
#define TILE_GATHER(AF, RT, THR, TIDX) do {                                     \
    f32x16 acc_;                                                                \
    _Pragma("unroll") for (int i_ = 0; i_ < 16; ++i_) acc_[i_] = 0.f;           \
    _Pragma("unroll") for (int k_ = 0; k_ < 5; ++k_)                            \
        acc_ = __builtin_amdgcn_mfma_f32_32x32x16_bf16(AF[k_], bfrag[RT][k_],   \
                                                       acc_, 0, 0, 0);          \
    float m0_ = fmaxf(fmaxf(acc_[0], acc_[1]),  fmaxf(acc_[2], acc_[3]));       \
    float m1_ = fmaxf(fmaxf(acc_[4], acc_[5]),  fmaxf(acc_[6], acc_[7]));       \
    float m2_ = fmaxf(fmaxf(acc_[8], acc_[9]),  fmaxf(acc_[10], acc_[11]));     \
    float m3_ = fmaxf(fmaxf(acc_[12], acc_[13]), fmaxf(acc_[14], acc_[15]));    \
    float tm_ = fmaxf(fmaxf(m0_, m1_), fmaxf(m2_, m3_));                        \
    if (__any(tm_ >= (THR))) {                                                  \
        const int lr_ = (RT) * 32 + l31;                                        \
        _Pragma("unroll") for (int r_ = 0; r_ < 16; ++r_) {                     \
            if (acc_[r_] >= (THR)) {                                            \
                const int crow_ = (r_ & 3) + 8 * (r_ >> 2) + 4 * half;          \
                const int pos_ = atomicAdd(&scnt[lr_], 1);                      \
                if (pos_ < CAP)                                                 \
                    sslots[lr_][pos_] = candbase + (TIDX) * 32 + crow_;         \
            }                                                                   \
        }                                                                       \
    }                                                                           \
} while (0)

__global__ __launch_bounds__(512, 4)
void vq_fused_kernel(const unsigned short* __restrict__ ebuf,
                     const unsigned short* __restrict__ xbuf,
                     const float* __restrict__ x, const float* __restrict__ cb,
                     const float* __restrict__ norms, const float* __restrict__ sxa,
                     float* __restrict__ out_q, float* __restrict__ out_idx,
                     float* __restrict__ block_loss) {
    const int tid  = threadIdx.x;
    const int lane = tid & 63;
    const int wid  = tid >> 6;          // 0..7: candidate split
    const int half = lane >> 5;
    const int l31  = lane & 31;
    const int rowbase  = blockIdx.x * ROWS_PB;
    const int candbase = wid * 1024;

    __shared__ float sm[WAVES][2][32];
    __shared__ float sthr[ROWS_PB];
    __shared__ int   scnt[ROWS_PB];
    __shared__ int   sslots[ROWS_PB][CAP];
    __shared__ float wloss[WAVES];

    if (tid < ROWS_PB) scnt[tid] = 0;

    // B fragments: 64 rows (2 rt x 32), persistent
    bf16x8 bfrag[2][5];
#pragma unroll
    for (int rt = 0; rt < 2; ++rt)
#pragma unroll
        for (int ks = 0; ks < 5; ++ks)
            bfrag[rt][ks] = *reinterpret_cast<const bf16x8*>(
                xbuf + (size_t)(rowbase + rt * 32 + l31) * KPAD + ks * 16 + half * 8);

    const unsigned short* abase = ebuf + (size_t)(candbase + l31) * KPAD + half * 8;

    // ---- pass 1: per-row max, reg-double-buffered A ----
    bf16x8 a0[5], a1[5];
#pragma unroll
    for (int ks = 0; ks < 5; ++ks)
        a0[ks] = *reinterpret_cast<const bf16x8*>(abase + ks * 16);

    float vmA0 = -FLTMAX, vmA1 = -FLTMAX, vmB0 = -FLTMAX, vmB1 = -FLTMAX;
    for (int t = 0; t < NT; t += 2) {
        const unsigned short* ap1 = abase + (size_t)(t + 1) * 32 * KPAD;
#pragma unroll
        for (int ks = 0; ks < 5; ++ks)
            a1[ks] = *reinterpret_cast<const bf16x8*>(ap1 + ks * 16);
        TILE_MAX(a0, 0, vmA0);
        TILE_MAX(a0, 1, vmA1);
        // t+2 over-read at t=NT-2 lands in xbuf (mapped ws) and is never used
        const unsigned short* ap2 = abase + (size_t)(t + 2) * 32 * KPAD;
#pragma unroll
        for (int ks = 0; ks < 5; ++ks)
            a0[ks] = *reinterpret_cast<const bf16x8*>(ap2 + ks * 16);
        TILE_MAX(a1, 0, vmB0);
        TILE_MAX(a1, 1, vmB1);
    }
    float vmax0 = fmaxf(vmA0, vmB0);
    float vmax1 = fmaxf(vmA1, vmB1);
    vmax0 = fmaxf(vmax0, __shfl_xor(vmax0, 32));
    vmax1 = fmaxf(vmax1, __shfl_xor(vmax1, 32));
    if (half == 0) { sm[wid][0][l31] = vmax0; sm[wid][1][l31] = vmax1; }
    __syncthreads();
    if (tid < ROWS_PB) {
        const int rt = tid >> 5, xr = tid & 31;
        float m = sm[0][rt][xr];
#pragma unroll
        for (int w = 1; w < WAVES; ++w) m = fmaxf(m, sm[w][rt][xr]);
        sthr[tid] = m - TMARGIN;
    }
    __syncthreads();
    const float thr0 = sthr[l31];
    const float thr1 = sthr[32 + l31];

    // ---- pass 2: recompute + gather into LDS shortlist ----
#pragma unroll
    for (int ks = 0; ks < 5; ++ks)
        a0[ks] = *reinterpret_cast<const bf16x8*>(abase + ks * 16);
    for (int t = 0; t < NT; t += 2) {
        const unsigned short* ap1 = abase + (size_t)(t + 1) * 32 * KPAD;
#pragma unroll
        for (int ks = 0; ks < 5; ++ks)
            a1[ks] = *reinterpret_cast<const bf16x8*>(ap1 + ks * 16);
        TILE_GATHER(a0, 0, thr0, t);
        TILE_GATHER(a0, 1, thr1, t);
        const unsigned short* ap2 = abase + (size_t)(t + 2) * 32 * KPAD;
#pragma unroll
        for (int ks = 0; ks < 5; ++ks)
            a0[ks] = *reinterpret_cast<const bf16x8*>(ap2 + ks * 16);
        TILE_GATHER(a1, 0, thr0, t + 1);
        TILE_GATHER(a1, 1, thr1, t + 1);
    }
    __syncthreads();

    // ---- fused finalize: wave handles 8 rows; exact rescore + gather + loss ----
    float lsum = 0.f;
    for (int i = 0; i < 8; ++i) {
        const int lr = wid * 8 + i;
        const int r  = rowbase + lr;
        const int c0 = scnt[lr];
        const bool okc = (c0 <= CAP);
        const int nlist = okc ? c0 : NUM_E;   // overflow -> wave-parallel full scan
        const float sx = sxa[r];
        float4 xr[16];
        const float4* xp = reinterpret_cast<const float4*>(x + (size_t)r * DIM);
#pragma unroll
        for (int c = 0; c < 16; ++c) xr[c] = xp[c];
        float best = FLTMAX;
        int bi = 0x7FFFFFFF;
        for (int j = lane; j < nlist; j += 64) {
            const int k = okc ? sslots[lr][j] : j;
            const float* ep = cb + (size_t)k * DIM;
            float dot = 0.f;   // sequential fmaf chain d=0..63 (exact replication)
#pragma unroll
            for (int c = 0; c < 16; ++c) {
                dot = fmaf(xr[c].x, ep[4 * c + 0], dot);
                dot = fmaf(xr[c].y, ep[4 * c + 1], dot);
                dot = fmaf(xr[c].z, ep[4 * c + 2], dot);
                dot = fmaf(xr[c].w, ep[4 * c + 3], dot);
            }
            const float t1 = __fadd_rn(sx, norms[k]);
            const float d2 = __fadd_rn(dot, dot);
            const float sc = __fsub_rn(t1, d2);
            if (sc < best || (sc == best && k < bi)) { best = sc; bi = k; }
        }
#pragma unroll
        for (int off = 1; off < 64; off <<= 1) {   // lexicographic first-min
            const float s2 = __shfl_xor(best, off);
            const int   i2 = __shfl_xor(bi, off);
            if (s2 < best || (s2 == best && i2 < bi)) { best = s2; bi = i2; }
        }
        const float ed = cb[(size_t)bi * DIM + lane];
        const float xd = x[(size_t)r * DIM + lane];
        out_q[(size_t)r * DIM + lane] = ed;
        if (lane == 0) out_idx[r] = (float)bi;
        const float dd = ed - xd;
        lsum = fmaf(dd, dd, lsum);
    }
#pragma unroll
    for (int off = 1; off < 64; off <<= 1) lsum += __shfl_xor(lsum, off);
    if (lane == 0) wloss[wid] = lsum;
    __syncthreads();
    if (tid == 0) {
        float s = 0.f;
#pragma unroll
        for (int w = 0; w < WAVES; ++w) s += wloss[w];
        block_loss[blockIdx.x] = s;
    }
}

__global__ __launch_bounds__(256)
void vq_loss_kernel(const float* __restrict__ block_loss,
                    float* __restrict__ out_loss) {
    float s = 0.f;
    for (int i = threadIdx.x; i < NROWS / ROWS_PB; i += 256) s += block_loss[i];
#pragma unroll
    for (int off = 1; off < 64; off <<= 1) s += __shfl_xor(s, off);
    __shared__ float wsum[4];
    const int lane = threadIdx.x & 63, wv = threadIdx.x >> 6;
    if (lane == 0) wsum[wv] = s;
    __syncthreads();
    if (threadIdx.x == 0)
        *out_loss = ((wsum[0] + wsum[1]) + (wsum[2] + wsum[3])) * (1.25f / (float)NELEM);
}

extern "C" void kernel_launch(void* const* d_in, const int* in_sizes, int n_in,
                              void* d_out, int out_size, void* d_ws, size_t ws_size,
                              hipStream_t stream) {
    const float* x  = (const float*)d_in[0];
    const float* cb = (const float*)d_in[1];

    float* out_q    = (float*)d_out;
    float* out_loss = (float*)d_out + NELEM;
    float* out_idx  = (float*)d_out + NELEM + 1;

    float* wsf        = (float*)d_ws;
    float* block_loss = wsf;                              // 512
    float* norms      = wsf + 512;                        // 8192
    float* sxa        = norms + NUM_E;                    // 32768
    unsigned short* ebuf = (unsigned short*)(sxa + NROWS);   // 8192*80 (16B-aligned)
    unsigned short* xbuf = ebuf + (size_t)NUM_E * KPAD;      // 32768*80

    vq_prep_cb<<<NUM_E / 256, 256, 0, stream>>>(cb, norms, ebuf);
    vq_prep_x<<<NROWS / 256, 256, 0, stream>>>(x, sxa, xbuf);
    vq_fused_kernel<<<NROWS / ROWS_PB, 512, 0, stream>>>(ebuf, xbuf, x, cb, norms, sxa,
                                                         out_q, out_idx, block_loss);
    vq_loss_kernel<<<1, 256, 0, stream>>>(block_loss, out_loss);
}